// Round 5
// baseline (169.185 us; speedup 1.0000x reference)
//
#include <hip/hip_runtime.h>
#include <stdint.h>

#define NROW 2048
#define D_IM 1024
#define D_CLI 64
#define EPSF 1e-12f
#define NN ((size_t)NROW * (size_t)NROW)
#define GRID_GEMM 800
#define PIM_STRIDE 4352   // 4096 + 256 pad: breaks 4KB channel aliasing

typedef __attribute__((ext_vector_type(8))) short bf16x8;
typedef __attribute__((ext_vector_type(4))) float f32x4;

// ws layout (bytes):
//   PACKED   [0,48)
//   CNT      [64,80)
//   CAT      [128,8320)
//   LISTS    [8320,32896)
//   POS      [32896,41088)
//   COLINFO  [41216,65792)
//   INVIM    [65792,73984)
//   INVCLI   [73984,82176)
//   PIM      [82176, 82176+2048*4352)          padded rows
//   PCLI     [8995072, 8995072+2048*256)
//   SC       [9519360, ...)                    compact bf16 S, worst ~6 MB
#define OFF_PACKED   0
#define OFF_CNT      64
#define OFF_CAT      128
#define OFF_LISTS    8320
#define OFF_POS      32896
#define OFF_COLINFO  41216
#define OFF_INVIM    65792
#define OFF_INVCLI   73984
#define OFF_PIM      82176
#define OFF_PCLI     8995072
#define OFF_SC       9519360

__device__ __forceinline__ unsigned int enc_f32(float x) {
    unsigned int u = __float_as_uint(x);
    return (u & 0x80000000u) ? ~u : (u | 0x80000000u);
}
__device__ __forceinline__ unsigned short bf16rn(float x) {
    unsigned int u = __float_as_uint(x);
    return (unsigned short)((u + 0x7FFFu + ((u >> 16) & 1u)) >> 16);
}
__device__ __forceinline__ float bf16tof(unsigned short h) {
    return __uint_as_float(((unsigned int)h) << 16);
}

// Fused prep+scan: blocks 0..2047 per-row norms + bf16 hi/lo pack;
// block 2048 category scan/compaction/init. No fill blocks here.
__global__ __launch_bounds__(256)
void prepscan_kernel(const float* __restrict__ phi_im,
                     const float* __restrict__ phi_cli,
                     const int* __restrict__ t,
                     const int* __restrict__ traumatic,
                     float* __restrict__ inv_im,
                     float* __restrict__ inv_cli,
                     char* __restrict__ pim,
                     char* __restrict__ pcli,
                     int* __restrict__ cnt,
                     int* __restrict__ catArr,
                     int* __restrict__ lists,
                     int* __restrict__ posIn,
                     unsigned int* __restrict__ colinfo,
                     unsigned long long* __restrict__ packed) {
    __shared__ unsigned long long shmem[256];
    const int tid = threadIdx.x;

    if (blockIdx.x == NROW) {
        int cats[8];
        unsigned long long mycnt = 0;
        #pragma unroll
        for (int e = 0; e < 8; e++) {
            int r = tid * 8 + e;
            int t1 = t[2 * r + 1];
            int tr = traumatic[r];
            int c = (t1 == 1) ? 1 : ((t1 == 2) ? 2 : ((tr == 1) ? 0 : 3));
            cats[e] = c;
            catArr[r] = c;
            if (c < 3) mycnt += 1ULL << (21 * c);
        }
        shmem[tid] = mycnt;
        __syncthreads();
        for (int off = 1; off < 256; off <<= 1) {
            unsigned long long v = (tid >= off) ? shmem[tid - off] : 0ULL;
            __syncthreads();
            shmem[tid] += v;
            __syncthreads();
        }
        unsigned long long excl = shmem[tid] - mycnt;
        unsigned long long tot = shmem[255];
        unsigned int loc[3];
        #pragma unroll
        for (int c = 0; c < 3; c++)
            loc[c] = (unsigned int)(excl >> (21 * c)) & 0x1FFFFFu;
        #pragma unroll
        for (int e = 0; e < 8; e++) {
            int r = tid * 8 + e;
            int c = cats[e];
            unsigned int slot = 0xFFFFFFFFu;
            if (c < 3) {
                slot = loc[c]++;
                lists[c * 2048 + slot] = r;
                posIn[r] = (int)slot;
            }
            colinfo[0 * 2048 + r] = (c == 1) ? slot : 0xFFFFFFFFu;
            colinfo[1 * 2048 + r] = (c == 2) ? slot : 0xFFFFFFFFu;
            colinfo[2 * 2048 + r] = (c == 2) ? slot : 0xFFFFFFFFu;
        }
        if (tid == 0) {
            cnt[0] = (int)(tot & 0x1FFFFFu);
            cnt[1] = (int)((tot >> 21) & 0x1FFFFFu);
            cnt[2] = (int)((tot >> 42) & 0x1FFFFFu);
            cnt[3] = 0;
        }
        if (tid < 6) packed[tid] = 0xFFFFFFFFFFFFFFFFULL;
        return;
    }

    float* sred = (float*)shmem;
    const int r = blockIdx.x;

    float4 v = ((const float4*)(phi_im + (size_t)r * D_IM))[tid];
    float a[4] = {v.x, v.y, v.z, v.w};
    unsigned short h4[4], l4[4];
    #pragma unroll
    for (int e = 0; e < 4; e++) {
        h4[e] = bf16rn(a[e]);
        l4[e] = bf16rn(a[e] - bf16tof(h4[e]));
    }
    {
        char* rowb = pim + (size_t)r * PIM_STRIDE + (tid >> 1) * 32 + (tid & 1) * 8;
        *(ushort4*)rowb = make_ushort4(h4[0], h4[1], h4[2], h4[3]);
        *(ushort4*)(rowb + 16) = make_ushort4(l4[0], l4[1], l4[2], l4[3]);
    }
    sred[tid] = a[0] * a[0] + a[1] * a[1] + a[2] * a[2] + a[3] * a[3];
    __syncthreads();
    for (int off = 128; off > 0; off >>= 1) {
        if (tid < off) sred[tid] += sred[tid + off];
        __syncthreads();
    }
    if (tid == 0) inv_im[r] = 1.0f / fmaxf(sqrtf(sred[0]), EPSF);

    if (tid < 16) {
        float4 c = ((const float4*)(phi_cli + (size_t)r * D_CLI))[tid];
        float b[4] = {c.x, c.y, c.z, c.w};
        unsigned short ch[4], cl[4];
        #pragma unroll
        for (int e = 0; e < 4; e++) {
            ch[e] = bf16rn(b[e]);
            cl[e] = bf16rn(b[e] - bf16tof(ch[e]));
        }
        char* rowb = pcli + (size_t)r * 256 + (tid >> 1) * 32 + (tid & 1) * 8;
        *(ushort4*)rowb = make_ushort4(ch[0], ch[1], ch[2], ch[3]);
        *(ushort4*)(rowb + 16) = make_ushort4(cl[0], cl[1], cl[2], cl[3]);
        // cli inv-norm from the same registers: shuffle-reduce across 16 lanes
        float cs = b[0] * b[0] + b[1] * b[1] + b[2] * b[2] + b[3] * b[3];
        #pragma unroll
        for (int off = 8; off > 0; off >>= 1) cs += __shfl_down(cs, off, 16);
        if (tid == 0) inv_cli[r] = 1.0f / fmaxf(sqrtf(cs), EPSF);
    }
}

// LDS-staged 4-wave output-split gather-GEMM (identical math to round 4).
// Blocks >= GRID_GEMM: UNCONDITIONAL zero-fill of all 6 output matrices
// (2 rows per block, zero loads, zero branches) — the writer overwrites
// valid rows afterwards. Fill HBM writes stream under the GEMM compute.
#define MFMA_SET(AH, AL, BH, BL)                                           \
    _Pragma("unroll") for (int lm = 0; lm < 2; lm++)                       \
        _Pragma("unroll") for (int ln = 0; ln < 2; ln++) {                 \
            acc[lm][ln] = __builtin_amdgcn_mfma_f32_16x16x32_bf16(         \
                AH[lm], BH[ln], acc[lm][ln], 0, 0, 0);                     \
            acc[lm][ln] = __builtin_amdgcn_mfma_f32_16x16x32_bf16(         \
                AH[lm], BL[ln], acc[lm][ln], 0, 0, 0);                     \
            acc[lm][ln] = __builtin_amdgcn_mfma_f32_16x16x32_bf16(         \
                AL[lm], BH[ln], acc[lm][ln], 0, 0, 0);                     \
        }

#define LOAD_REGS(RA, RB, OFF)                                             \
    RA[0] = *(const f32x4*)(pX + gA0 + (OFF));                             \
    RA[1] = *(const f32x4*)(pX + gA1 + (OFF));                             \
    RB[0] = *(const f32x4*)(pX + gB0 + (OFF));                             \
    RB[1] = *(const f32x4*)(pX + gB1 + (OFF));

#define STAGE_WRITE(B, RA, RB)                                             \
    *(f32x4*)(&sT[B][0][my_e][my_r * 16]) = RA[0];                         \
    *(f32x4*)(&sT[B][0][my_e][(32 + my_r) * 16]) = RA[1];                  \
    *(f32x4*)(&sT[B][1][my_e][my_r * 16]) = RB[0];                         \
    *(f32x4*)(&sT[B][1][my_e][(32 + my_r) * 16]) = RB[1];

#define COMPUTE(B)                                                         \
    {                                                                      \
        bf16x8 AH[2], AL[2], BH[2], BL[2];                                 \
        _Pragma("unroll") for (int q = 0; q < 2; q++) {                    \
            AH[q] = *(const bf16x8*)(&sT[B][0][2 * quad][aoff[q]]);        \
            AL[q] = *(const bf16x8*)(&sT[B][0][2 * quad + 1][aoff[q]]);    \
            BH[q] = *(const bf16x8*)(&sT[B][1][2 * quad][boff[q]]);        \
            BL[q] = *(const bf16x8*)(&sT[B][1][2 * quad + 1][boff[q]]);    \
        }                                                                  \
        MFMA_SET(AH, AL, BH, BL)                                           \
    }

__global__ __launch_bounds__(256, 3)
void gemm_kernel(const char* __restrict__ pim,
                 const char* __restrict__ pcli,
                 const float* __restrict__ inv_im,
                 const float* __restrict__ inv_cli,
                 const int* __restrict__ cnt,
                 const int* __restrict__ lists,
                 unsigned short* __restrict__ Sc,
                 float* __restrict__ out,
                 unsigned long long* __restrict__ packed) {
    const int tid = threadIdx.x;

    // ---- unconditional zero-fill branch: 2 rows per block, no loads ----
    if (blockIdx.x >= GRID_GEMM) {
        const int idx = blockIdx.x - GRID_GEMM;   // 0 .. 6143
        const int pzf = idx >> 10;                // 0..5
        const int rp = idx & 1023;                // row pair
        float* orow = out + (size_t)pzf * NN + (size_t)(2 * rp) * NROW;
        const f32x4 z4 = (f32x4){0.f, 0.f, 0.f, 0.f};
        #pragma unroll
        for (int s = 0; s < 4; s++)
            __builtin_nontemporal_store(z4, (f32x4*)orow + tid + s * 256);
        return;
    }

    __shared__ float sIA[64], sIB[64];
    __shared__ int sRA[64], sRB[64];
    // [buf][A/B][e-slot 0..7][65 rows x 16B]  (pad row-dim 64->65: bank-opt)
    __shared__ __align__(16) char sT[2][2][8][1040];

    const int n0 = cnt[0], n1 = cnt[1], n2 = cnt[2];
    const int tA = (n0 + 63) >> 6, tB = (n1 + 63) >> 6, tC = (n2 + 63) >> 6;
    const int T0 = tA * tB, T1 = tA * tC, T2 = tB * tC;
    const int tot = T0 + T1 + T2;
    int bid = blockIdx.x;
    if (bid >= 2 * tot) return;
    int z = 0;
    if (bid >= tot) { z = 1; bid -= tot; }
    const size_t s0 = (size_t)(tA << 6) * (tB << 6);
    const size_t s1 = (size_t)(tA << 6) * (tC << 6);
    const size_t s2 = (size_t)(tB << 6) * (tC << 6);
    size_t scoff = z ? (s0 + s1 + s2) : 0;
    int gx, nA, nB, nBpad, pp;
    const int *lA, *lB;
    if (bid < T0)           { pp = 0; gx = tB; nA = n0; nB = n1; lA = lists;        lB = lists + 2048; nBpad = tB << 6; }
    else if (bid < T0 + T1) { bid -= T0;      scoff += s0;      pp = 1; gx = tC; nA = n0; nB = n2; lA = lists;        lB = lists + 4096; nBpad = tC << 6; }
    else                    { bid -= T0 + T1; scoff += s0 + s1; pp = 2; gx = tC; nA = n1; nB = n2; lA = lists + 2048; lB = lists + 4096; nBpad = tC << 6; }
    const int by = bid / gx, bx = bid % gx;
    const int i0 = by << 6, j0 = bx << 6;
    const int pz = z * 3 + pp;

    const char* __restrict__ pX = z ? pcli : pim;
    const float* __restrict__ inv = z ? inv_cli : inv_im;
    const int nst = z ? (D_CLI / 32) : (D_IM / 32);   // stages = K-steps
    const size_t stride = z ? 256 : PIM_STRIDE;
    const int lane = tid & 63;
    const int wid = tid >> 6;
    const int wr = wid >> 1;          // quadrant row (0/1)
    const int wc = wid & 1;           // quadrant col (0/1)

    if (tid < 64) {
        int ia = lA[min(i0 + tid, nA - 1)];
        int ib = lB[min(j0 + tid, nB - 1)];
        sRA[tid] = ia; sRB[tid] = ib;
        sIA[tid] = inv[ia]; sIB[tid] = inv[ib];
    }
    __syncthreads();

    const int mrow = lane & 15;
    const int quad = lane >> 4;

    // staging mapping: 8 threads per row (coalesced 128B), rows my_r & 32+my_r
    const int my_e = tid & 7;
    const int my_r = tid >> 3;        // 0..31
    const size_t gA0 = (size_t)sRA[my_r] * stride + my_e * 16;
    const size_t gA1 = (size_t)sRA[32 + my_r] * stride + my_e * 16;
    const size_t gB0 = (size_t)sRB[my_r] * stride + my_e * 16;
    const size_t gB1 = (size_t)sRB[32 + my_r] * stride + my_e * 16;

    // fragment LDS offsets (bytes within an e-slot)
    int aoff[2], boff[2];
    #pragma unroll
    for (int q = 0; q < 2; q++) {
        aoff[q] = ((wr * 2 + q) * 16 + mrow) * 16;
        boff[q] = ((wc * 2 + q) * 16 + mrow) * 16;
    }

    f32x4 acc[2][2];
    #pragma unroll
    for (int lm = 0; lm < 2; lm++)
        #pragma unroll
        for (int ln = 0; ln < 2; ln++)
            acc[lm][ln] = (f32x4){0.f, 0.f, 0.f, 0.f};

    f32x4 ra0[2], rb0[2], ra1[2], rb1[2];
    LOAD_REGS(ra0, rb0, 0);
    LOAD_REGS(ra1, rb1, 128);

    for (int st = 0; st < nst; st += 2) {
        STAGE_WRITE(0, ra0, rb0);
        __syncthreads();
        if (st + 2 < nst) { LOAD_REGS(ra0, rb0, (size_t)(st + 2) * 128); }
        COMPUTE(0);
        __syncthreads();

        STAGE_WRITE(1, ra1, rb1);
        __syncthreads();
        if (st + 3 < nst) { LOAD_REGS(ra1, rb1, (size_t)(st + 3) * 128); }
        COMPUTE(1);
        __syncthreads();
    }

    // Epilogue: scale (f32), argmin on exact f32, store bf16 to Sc.
    unsigned long long best = 0xFFFFFFFFFFFFFFFFULL;
    #pragma unroll
    for (int lm = 0; lm < 2; lm++)
        #pragma unroll
        for (int ln = 0; ln < 2; ln++) {
            const int cloc = (wc * 2 + ln) * 16 + mrow;
            const float ivb = sIB[cloc];
            const unsigned int jcol = (unsigned int)sRB[cloc];
            #pragma unroll
            for (int rr = 0; rr < 4; rr++) {
                const int rloc = (wr * 2 + lm) * 16 + quad * 4 + rr;
                float sv = acc[lm][ln][rr] * (sIA[rloc] * ivb);
                Sc[scoff + (size_t)(i0 + rloc) * nBpad + (j0 + cloc)] = bf16rn(sv);
                unsigned long long pk =
                    ((unsigned long long)enc_f32(sv) << 32) |
                    ((unsigned int)sRA[rloc] * (unsigned int)NROW + jcol);
                if (pk < best) best = pk;
            }
        }
    #pragma unroll
    for (int off = 32; off > 0; off >>= 1) {
        unsigned long long o = __shfl_down(best, off, 64);
        if (o < best) best = o;
    }
    if (lane == 0) atomicMin(&packed[pz], best);
}

// Writer: one block per (pz, compact-slot k). Valid slots (k < n_valid)
// gather the compact bf16 row (Sc row index == k, since posIn[lists[c][k]]
// == k) and stream f32 over the zero-filled row. Block 6*NROW finalizes.
__global__ __launch_bounds__(256)
void writer_kernel(const unsigned short* __restrict__ Sc,
                   const int* __restrict__ cnt,
                   const int* __restrict__ lists,
                   const unsigned int* __restrict__ colinfo,
                   float* __restrict__ out,
                   const unsigned long long* __restrict__ packed) {
    const int b = blockIdx.x;
    const int tid = threadIdx.x;
    if (b == 6 * NROW) {
        const int p = tid;
        if (p < 6) {
            unsigned long long pk = packed[p];
            float v;
            unsigned int flat;
            if (pk == 0xFFFFFFFFFFFFFFFFULL) { v = __builtin_huge_valf(); flat = 0u; }
            else {
                unsigned int key = (unsigned int)(pk >> 32);
                flat = (unsigned int)pk;
                unsigned int bits = (key & 0x80000000u) ? (key ^ 0x80000000u) : ~key;
                v = __uint_as_float(bits);
            }
            out[6 * NN + p] = v;
            out[6 * NN + 6 + 2 * p + 0] = (float)(flat >> 11);
            out[6 * NN + 6 + 2 * p + 1] = (float)(flat & 2047u);
        }
        return;
    }
    const int pz = b >> 11;            // 0..5
    const int k = b & 2047;            // compact row slot
    const int z = pz / 3, p = pz - 3 * z;

    const int n0 = cnt[0], n1 = cnt[1], n2 = cnt[2];
    const int nv = (p == 2) ? n1 : n0;
    if (k >= nv) return;               // no such valid row
    const int row = lists[((p == 2) ? 1 : 0) * 2048 + k];

    float* orow = out + (size_t)pz * NN + (size_t)row * NROW;

    const int tA = (n0 + 63) >> 6, tB = (n1 + 63) >> 6, tC = (n2 + 63) >> 6;
    const size_t s0 = (size_t)(tA << 6) * (tB << 6);
    const size_t s1 = (size_t)(tA << 6) * (tC << 6);
    const size_t s2 = (size_t)(tB << 6) * (tC << 6);
    size_t scoff = z ? (s0 + s1 + s2) : 0;
    int nBpad;
    if (p == 0)      { nBpad = tB << 6; }
    else if (p == 1) { scoff += s0;      nBpad = tC << 6; }
    else             { scoff += s0 + s1; nBpad = tC << 6; }

    const unsigned short* srow = Sc + scoff + (size_t)k * nBpad;
    const uint4* cinfo4 = (const uint4*)(colinfo + p * 2048);

    #pragma unroll
    for (int seg = 0; seg < 2; seg++) {
        const int j4 = tid + seg * 256;
        uint4 inf = cinfo4[j4];
        f32x4 vv;
        vv[0] = (inf.x != 0xFFFFFFFFu) ? bf16tof(srow[inf.x]) : 0.f;
        vv[1] = (inf.y != 0xFFFFFFFFu) ? bf16tof(srow[inf.y]) : 0.f;
        vv[2] = (inf.z != 0xFFFFFFFFu) ? bf16tof(srow[inf.z]) : 0.f;
        vv[3] = (inf.w != 0xFFFFFFFFu) ? bf16tof(srow[inf.w]) : 0.f;
        __builtin_nontemporal_store(vv, (f32x4*)orow + j4);
    }
}

extern "C" void kernel_launch(void* const* d_in, const int* in_sizes, int n_in,
                              void* d_out, int out_size, void* d_ws, size_t ws_size,
                              hipStream_t stream) {
    const float* phi_im = (const float*)d_in[0];
    const float* phi_cli = (const float*)d_in[1];
    const int* t = (const int*)d_in[2];
    const int* traumatic = (const int*)d_in[3];
    float* out = (float*)d_out;

    char* ws = (char*)d_ws;
    unsigned long long* packed = (unsigned long long*)(ws + OFF_PACKED);
    int* cnt = (int*)(ws + OFF_CNT);
    int* catArr = (int*)(ws + OFF_CAT);
    int* lists = (int*)(ws + OFF_LISTS);
    int* posIn = (int*)(ws + OFF_POS);
    unsigned int* colinfo = (unsigned int*)(ws + OFF_COLINFO);
    float* inv_im = (float*)(ws + OFF_INVIM);
    float* inv_cli = (float*)(ws + OFF_INVCLI);
    char* pim = ws + OFF_PIM;
    char* pcli = ws + OFF_PCLI;
    unsigned short* Sc = (unsigned short*)(ws + OFF_SC);

    prepscan_kernel<<<NROW + 1, 256, 0, stream>>>(
        phi_im, phi_cli, t, traumatic, inv_im, inv_cli, pim, pcli,
        cnt, catArr, lists, posIn, colinfo, packed);
    gemm_kernel<<<GRID_GEMM + 6 * 1024, 256, 0, stream>>>(
        pim, pcli, inv_im, inv_cli, cnt, lists, Sc, out, packed);
    writer_kernel<<<6 * NROW + 1, 256, 0, stream>>>(Sc, cnt, lists,
                                                    colinfo, out, packed);
}

// Round 6
// 163.039 us; speedup vs baseline: 1.0377x; 1.0377x over previous
//
#include <hip/hip_runtime.h>
#include <stdint.h>

#define NROW 2048
#define D_IM 1024
#define D_CLI 64
#define EPSF 1e-12f
#define NN ((size_t)NROW * (size_t)NROW)
#define GRID_GEMM 800
#define PIM_STRIDE 4352   // 4096 + 256 pad: breaks 4KB channel aliasing

typedef __attribute__((ext_vector_type(8))) short bf16x8;
typedef __attribute__((ext_vector_type(4))) float f32x4;

// ws layout (bytes):
//   PACKED   [0,48)
//   CNT      [64,80)
//   CAT      [128,8320)
//   LISTS    [8320,32896)
//   POS      [32896,41088)
//   COLINFO  [41216,65792)
//   INVIM    [65792,73984)
//   INVCLI   [73984,82176)
//   PIM      [82176, 82176+2048*4352)          padded rows
//   PCLI     [8995072, 8995072+2048*256)
//   SC       [9519360, ...)                    compact bf16 S, worst ~6 MB
#define OFF_PACKED   0
#define OFF_CNT      64
#define OFF_CAT      128
#define OFF_LISTS    8320
#define OFF_POS      32896
#define OFF_COLINFO  41216
#define OFF_INVIM    65792
#define OFF_INVCLI   73984
#define OFF_PIM      82176
#define OFF_PCLI     8995072
#define OFF_SC       9519360

__device__ __forceinline__ unsigned int enc_f32(float x) {
    unsigned int u = __float_as_uint(x);
    return (u & 0x80000000u) ? ~u : (u | 0x80000000u);
}
__device__ __forceinline__ unsigned short bf16rn(float x) {
    unsigned int u = __float_as_uint(x);
    return (unsigned short)((u + 0x7FFFu + ((u >> 16) & 1u)) >> 16);
}
__device__ __forceinline__ float bf16tof(unsigned short h) {
    return __uint_as_float(((unsigned int)h) << 16);
}

// Prep+scan: blocks 0..511 handle 4 rows each (one row per wave, zero
// barriers, shuffle-only norm reduction); block 512 does the category
// scan/compaction/init.
__global__ __launch_bounds__(256)
void prepscan_kernel(const float* __restrict__ phi_im,
                     const float* __restrict__ phi_cli,
                     const int* __restrict__ t,
                     const int* __restrict__ traumatic,
                     float* __restrict__ inv_im,
                     float* __restrict__ inv_cli,
                     char* __restrict__ pim,
                     char* __restrict__ pcli,
                     int* __restrict__ cnt,
                     int* __restrict__ catArr,
                     int* __restrict__ lists,
                     int* __restrict__ posIn,
                     unsigned int* __restrict__ colinfo,
                     unsigned long long* __restrict__ packed) {
    const int tid = threadIdx.x;

    if (blockIdx.x == 512) {
        __shared__ unsigned long long shmem[256];
        int cats[8];
        unsigned long long mycnt = 0;
        #pragma unroll
        for (int e = 0; e < 8; e++) {
            int r = tid * 8 + e;
            int t1 = t[2 * r + 1];
            int tr = traumatic[r];
            int c = (t1 == 1) ? 1 : ((t1 == 2) ? 2 : ((tr == 1) ? 0 : 3));
            cats[e] = c;
            catArr[r] = c;
            if (c < 3) mycnt += 1ULL << (21 * c);
        }
        shmem[tid] = mycnt;
        __syncthreads();
        for (int off = 1; off < 256; off <<= 1) {
            unsigned long long v = (tid >= off) ? shmem[tid - off] : 0ULL;
            __syncthreads();
            shmem[tid] += v;
            __syncthreads();
        }
        unsigned long long excl = shmem[tid] - mycnt;
        unsigned long long tot = shmem[255];
        unsigned int loc[3];
        #pragma unroll
        for (int c = 0; c < 3; c++)
            loc[c] = (unsigned int)(excl >> (21 * c)) & 0x1FFFFFu;
        #pragma unroll
        for (int e = 0; e < 8; e++) {
            int r = tid * 8 + e;
            int c = cats[e];
            unsigned int slot = 0xFFFFFFFFu;
            if (c < 3) {
                slot = loc[c]++;
                lists[c * 2048 + slot] = r;
                posIn[r] = (int)slot;
            }
            colinfo[0 * 2048 + r] = (c == 1) ? slot : 0xFFFFFFFFu;
            colinfo[1 * 2048 + r] = (c == 2) ? slot : 0xFFFFFFFFu;
            colinfo[2 * 2048 + r] = (c == 2) ? slot : 0xFFFFFFFFu;
        }
        if (tid == 0) {
            cnt[0] = (int)(tot & 0x1FFFFFu);
            cnt[1] = (int)((tot >> 21) & 0x1FFFFFu);
            cnt[2] = (int)((tot >> 42) & 0x1FFFFFu);
            cnt[3] = 0;
        }
        if (tid < 6) packed[tid] = 0xFFFFFFFFFFFFFFFFULL;
        return;
    }

    const int lane = tid & 63;
    const int r = (blockIdx.x << 2) + (tid >> 6);   // one row per wave

    const float4* src = (const float4*)(phi_im + (size_t)r * D_IM);
    char* rowb = pim + (size_t)r * PIM_STRIDE;
    float ss = 0.f;
    #pragma unroll
    for (int k = 0; k < 4; k++) {
        const int f = lane + (k << 6);              // float4 index 0..255
        float4 v = src[f];
        float a[4] = {v.x, v.y, v.z, v.w};
        unsigned short h4[4], l4[4];
        #pragma unroll
        for (int e = 0; e < 4; e++) {
            h4[e] = bf16rn(a[e]);
            l4[e] = bf16rn(a[e] - bf16tof(h4[e]));
        }
        char* p = rowb + (f >> 1) * 32 + (f & 1) * 8;
        *(ushort4*)p = make_ushort4(h4[0], h4[1], h4[2], h4[3]);
        *(ushort4*)(p + 16) = make_ushort4(l4[0], l4[1], l4[2], l4[3]);
        ss += a[0] * a[0] + a[1] * a[1] + a[2] * a[2] + a[3] * a[3];
    }
    #pragma unroll
    for (int off = 32; off > 0; off >>= 1) ss += __shfl_down(ss, off, 64);
    if (lane == 0) inv_im[r] = 1.0f / fmaxf(sqrtf(ss), EPSF);

    if (lane < 16) {
        float4 c = ((const float4*)(phi_cli + (size_t)r * D_CLI))[lane];
        float b[4] = {c.x, c.y, c.z, c.w};
        unsigned short ch[4], cl[4];
        #pragma unroll
        for (int e = 0; e < 4; e++) {
            ch[e] = bf16rn(b[e]);
            cl[e] = bf16rn(b[e] - bf16tof(ch[e]));
        }
        char* crowb = pcli + (size_t)r * 256 + (lane >> 1) * 32 + (lane & 1) * 8;
        *(ushort4*)crowb = make_ushort4(ch[0], ch[1], ch[2], ch[3]);
        *(ushort4*)(crowb + 16) = make_ushort4(cl[0], cl[1], cl[2], cl[3]);
        float cs = b[0] * b[0] + b[1] * b[1] + b[2] * b[2] + b[3] * b[3];
        #pragma unroll
        for (int off = 8; off > 0; off >>= 1) cs += __shfl_down(cs, off, 16);
        if (lane == 0) inv_cli[r] = 1.0f / fmaxf(sqrtf(cs), EPSF);
    }
}

// LDS-staged 4-wave output-split gather-GEMM (identical math to rounds 4/5).
// Blocks >= GRID_GEMM: CONDITIONAL zero-fill of the 6 output matrices — only
// rows the writer will NOT overwrite (saves ~22 MB of redundant streaming).
// Fill HBM writes stream under the GEMM compute.
#define MFMA_SET(AH, AL, BH, BL)                                           \
    _Pragma("unroll") for (int lm = 0; lm < 2; lm++)                       \
        _Pragma("unroll") for (int ln = 0; ln < 2; ln++) {                 \
            acc[lm][ln] = __builtin_amdgcn_mfma_f32_16x16x32_bf16(         \
                AH[lm], BH[ln], acc[lm][ln], 0, 0, 0);                     \
            acc[lm][ln] = __builtin_amdgcn_mfma_f32_16x16x32_bf16(         \
                AH[lm], BL[ln], acc[lm][ln], 0, 0, 0);                     \
            acc[lm][ln] = __builtin_amdgcn_mfma_f32_16x16x32_bf16(         \
                AL[lm], BH[ln], acc[lm][ln], 0, 0, 0);                     \
        }

#define LOAD_REGS(RA, RB, OFF)                                             \
    RA[0] = *(const f32x4*)(pX + gA0 + (OFF));                             \
    RA[1] = *(const f32x4*)(pX + gA1 + (OFF));                             \
    RB[0] = *(const f32x4*)(pX + gB0 + (OFF));                             \
    RB[1] = *(const f32x4*)(pX + gB1 + (OFF));

#define STAGE_WRITE(B, RA, RB)                                             \
    *(f32x4*)(&sT[B][0][my_e][my_r * 16]) = RA[0];                         \
    *(f32x4*)(&sT[B][0][my_e][(32 + my_r) * 16]) = RA[1];                  \
    *(f32x4*)(&sT[B][1][my_e][my_r * 16]) = RB[0];                         \
    *(f32x4*)(&sT[B][1][my_e][(32 + my_r) * 16]) = RB[1];

#define COMPUTE(B)                                                         \
    {                                                                      \
        bf16x8 AH[2], AL[2], BH[2], BL[2];                                 \
        _Pragma("unroll") for (int q = 0; q < 2; q++) {                    \
            AH[q] = *(const bf16x8*)(&sT[B][0][2 * quad][aoff[q]]);        \
            AL[q] = *(const bf16x8*)(&sT[B][0][2 * quad + 1][aoff[q]]);    \
            BH[q] = *(const bf16x8*)(&sT[B][1][2 * quad][boff[q]]);        \
            BL[q] = *(const bf16x8*)(&sT[B][1][2 * quad + 1][boff[q]]);    \
        }                                                                  \
        MFMA_SET(AH, AL, BH, BL)                                           \
    }

__global__ __launch_bounds__(256, 3)
void gemm_kernel(const char* __restrict__ pim,
                 const char* __restrict__ pcli,
                 const float* __restrict__ inv_im,
                 const float* __restrict__ inv_cli,
                 const int* __restrict__ cnt,
                 const int* __restrict__ lists,
                 const int* __restrict__ catArr,
                 unsigned short* __restrict__ Sc,
                 float* __restrict__ out,
                 unsigned long long* __restrict__ packed) {
    const int tid = threadIdx.x;

    // ---- conditional zero-fill branch: 2 rows per block ----
    if (blockIdx.x >= GRID_GEMM) {
        const int idx = blockIdx.x - GRID_GEMM;   // 0 .. 6143
        const int pzf = idx >> 10;                // 0..5
        const int rp = idx & 1023;                // row pair
        const int p = pzf - 3 * (pzf / 3);
        const int rowcat = (p == 2) ? 1 : 0;
        const int r0 = rp << 1, r1 = r0 + 1;
        const int c0 = catArr[r0], c1 = catArr[r1];
        const f32x4 z4 = (f32x4){0.f, 0.f, 0.f, 0.f};
        if (c0 != rowcat) {
            float* orow = out + (size_t)pzf * NN + (size_t)r0 * NROW;
            __builtin_nontemporal_store(z4, (f32x4*)orow + tid);
            __builtin_nontemporal_store(z4, (f32x4*)orow + tid + 256);
        }
        if (c1 != rowcat) {
            float* orow = out + (size_t)pzf * NN + (size_t)r1 * NROW;
            __builtin_nontemporal_store(z4, (f32x4*)orow + tid);
            __builtin_nontemporal_store(z4, (f32x4*)orow + tid + 256);
        }
        return;
    }

    __shared__ float sIA[64], sIB[64];
    __shared__ int sRA[64], sRB[64];
    // [buf][A/B][e-slot 0..7][65 rows x 16B]  (pad row-dim 64->65: bank-opt)
    __shared__ __align__(16) char sT[2][2][8][1040];

    const int n0 = cnt[0], n1 = cnt[1], n2 = cnt[2];
    const int tA = (n0 + 63) >> 6, tB = (n1 + 63) >> 6, tC = (n2 + 63) >> 6;
    const int T0 = tA * tB, T1 = tA * tC, T2 = tB * tC;
    const int tot = T0 + T1 + T2;
    int bid = blockIdx.x;
    if (bid >= 2 * tot) return;
    int z = 0;
    if (bid >= tot) { z = 1; bid -= tot; }
    const size_t s0 = (size_t)(tA << 6) * (tB << 6);
    const size_t s1 = (size_t)(tA << 6) * (tC << 6);
    const size_t s2 = (size_t)(tB << 6) * (tC << 6);
    size_t scoff = z ? (s0 + s1 + s2) : 0;
    int gx, nA, nB, nBpad, pp;
    const int *lA, *lB;
    if (bid < T0)           { pp = 0; gx = tB; nA = n0; nB = n1; lA = lists;        lB = lists + 2048; nBpad = tB << 6; }
    else if (bid < T0 + T1) { bid -= T0;      scoff += s0;      pp = 1; gx = tC; nA = n0; nB = n2; lA = lists;        lB = lists + 4096; nBpad = tC << 6; }
    else                    { bid -= T0 + T1; scoff += s0 + s1; pp = 2; gx = tC; nA = n1; nB = n2; lA = lists + 2048; lB = lists + 4096; nBpad = tC << 6; }
    const int by = bid / gx, bx = bid % gx;
    const int i0 = by << 6, j0 = bx << 6;
    const int pz = z * 3 + pp;

    const char* __restrict__ pX = z ? pcli : pim;
    const float* __restrict__ inv = z ? inv_cli : inv_im;
    const int nst = z ? (D_CLI / 32) : (D_IM / 32);   // stages = K-steps
    const size_t stride = z ? 256 : PIM_STRIDE;
    const int lane = tid & 63;
    const int wid = tid >> 6;
    const int wr = wid >> 1;          // quadrant row (0/1)
    const int wc = wid & 1;           // quadrant col (0/1)

    if (tid < 64) {
        int ia = lA[min(i0 + tid, nA - 1)];
        int ib = lB[min(j0 + tid, nB - 1)];
        sRA[tid] = ia; sRB[tid] = ib;
        sIA[tid] = inv[ia]; sIB[tid] = inv[ib];
    }
    __syncthreads();

    const int mrow = lane & 15;
    const int quad = lane >> 4;

    // staging mapping: 8 threads per row (coalesced 128B), rows my_r & 32+my_r
    const int my_e = tid & 7;
    const int my_r = tid >> 3;        // 0..31
    const size_t gA0 = (size_t)sRA[my_r] * stride + my_e * 16;
    const size_t gA1 = (size_t)sRA[32 + my_r] * stride + my_e * 16;
    const size_t gB0 = (size_t)sRB[my_r] * stride + my_e * 16;
    const size_t gB1 = (size_t)sRB[32 + my_r] * stride + my_e * 16;

    // fragment LDS offsets (bytes within an e-slot)
    int aoff[2], boff[2];
    #pragma unroll
    for (int q = 0; q < 2; q++) {
        aoff[q] = ((wr * 2 + q) * 16 + mrow) * 16;
        boff[q] = ((wc * 2 + q) * 16 + mrow) * 16;
    }

    f32x4 acc[2][2];
    #pragma unroll
    for (int lm = 0; lm < 2; lm++)
        #pragma unroll
        for (int ln = 0; ln < 2; ln++)
            acc[lm][ln] = (f32x4){0.f, 0.f, 0.f, 0.f};

    f32x4 ra0[2], rb0[2], ra1[2], rb1[2];
    LOAD_REGS(ra0, rb0, 0);
    LOAD_REGS(ra1, rb1, 128);

    for (int st = 0; st < nst; st += 2) {
        STAGE_WRITE(0, ra0, rb0);
        __syncthreads();
        if (st + 2 < nst) { LOAD_REGS(ra0, rb0, (size_t)(st + 2) * 128); }
        COMPUTE(0);
        __syncthreads();

        STAGE_WRITE(1, ra1, rb1);
        __syncthreads();
        if (st + 3 < nst) { LOAD_REGS(ra1, rb1, (size_t)(st + 3) * 128); }
        COMPUTE(1);
        __syncthreads();
    }

    // Epilogue: scale (f32), argmin on exact f32, store bf16 to Sc.
    unsigned long long best = 0xFFFFFFFFFFFFFFFFULL;
    #pragma unroll
    for (int lm = 0; lm < 2; lm++)
        #pragma unroll
        for (int ln = 0; ln < 2; ln++) {
            const int cloc = (wc * 2 + ln) * 16 + mrow;
            const float ivb = sIB[cloc];
            const unsigned int jcol = (unsigned int)sRB[cloc];
            #pragma unroll
            for (int rr = 0; rr < 4; rr++) {
                const int rloc = (wr * 2 + lm) * 16 + quad * 4 + rr;
                float sv = acc[lm][ln][rr] * (sIA[rloc] * ivb);
                Sc[scoff + (size_t)(i0 + rloc) * nBpad + (j0 + cloc)] = bf16rn(sv);
                unsigned long long pk =
                    ((unsigned long long)enc_f32(sv) << 32) |
                    ((unsigned int)sRA[rloc] * (unsigned int)NROW + jcol);
                if (pk < best) best = pk;
            }
        }
    #pragma unroll
    for (int off = 32; off > 0; off >>= 1) {
        unsigned long long o = __shfl_down(best, off, 64);
        if (o < best) best = o;
    }
    if (lane == 0) atomicMin(&packed[pz], best);
}

// Writer: one block per (pz, compact-slot k). Valid slots (k < n_valid)
// gather the compact bf16 row (Sc row index == k, since slots are assigned
// in ascending row order) and stream f32. Block 6*NROW finalizes.
__global__ __launch_bounds__(256)
void writer_kernel(const unsigned short* __restrict__ Sc,
                   const int* __restrict__ cnt,
                   const int* __restrict__ lists,
                   const unsigned int* __restrict__ colinfo,
                   float* __restrict__ out,
                   const unsigned long long* __restrict__ packed) {
    const int b = blockIdx.x;
    const int tid = threadIdx.x;
    if (b == 6 * NROW) {
        const int p = tid;
        if (p < 6) {
            unsigned long long pk = packed[p];
            float v;
            unsigned int flat;
            if (pk == 0xFFFFFFFFFFFFFFFFULL) { v = __builtin_huge_valf(); flat = 0u; }
            else {
                unsigned int key = (unsigned int)(pk >> 32);
                flat = (unsigned int)pk;
                unsigned int bits = (key & 0x80000000u) ? (key ^ 0x80000000u) : ~key;
                v = __uint_as_float(bits);
            }
            out[6 * NN + p] = v;
            out[6 * NN + 6 + 2 * p + 0] = (float)(flat >> 11);
            out[6 * NN + 6 + 2 * p + 1] = (float)(flat & 2047u);
        }
        return;
    }
    const int pz = b >> 11;            // 0..5
    const int k = b & 2047;            // compact row slot
    const int z = pz / 3, p = pz - 3 * z;

    const int n0 = cnt[0], n1 = cnt[1], n2 = cnt[2];
    const int nv = (p == 2) ? n1 : n0;
    if (k >= nv) return;               // no such valid row
    const int row = lists[((p == 2) ? 1 : 0) * 2048 + k];

    float* orow = out + (size_t)pz * NN + (size_t)row * NROW;

    const int tA = (n0 + 63) >> 6, tB = (n1 + 63) >> 6, tC = (n2 + 63) >> 6;
    const size_t s0 = (size_t)(tA << 6) * (tB << 6);
    const size_t s1 = (size_t)(tA << 6) * (tC << 6);
    const size_t s2 = (size_t)(tB << 6) * (tC << 6);
    size_t scoff = z ? (s0 + s1 + s2) : 0;
    int nBpad;
    if (p == 0)      { nBpad = tB << 6; }
    else if (p == 1) { scoff += s0;      nBpad = tC << 6; }
    else             { scoff += s0 + s1; nBpad = tC << 6; }

    const unsigned short* srow = Sc + scoff + (size_t)k * nBpad;
    const uint4* cinfo4 = (const uint4*)(colinfo + p * 2048);

    #pragma unroll
    for (int seg = 0; seg < 2; seg++) {
        const int j4 = tid + seg * 256;
        uint4 inf = cinfo4[j4];
        f32x4 vv;
        vv[0] = (inf.x != 0xFFFFFFFFu) ? bf16tof(srow[inf.x]) : 0.f;
        vv[1] = (inf.y != 0xFFFFFFFFu) ? bf16tof(srow[inf.y]) : 0.f;
        vv[2] = (inf.z != 0xFFFFFFFFu) ? bf16tof(srow[inf.z]) : 0.f;
        vv[3] = (inf.w != 0xFFFFFFFFu) ? bf16tof(srow[inf.w]) : 0.f;
        __builtin_nontemporal_store(vv, (f32x4*)orow + j4);
    }
}

extern "C" void kernel_launch(void* const* d_in, const int* in_sizes, int n_in,
                              void* d_out, int out_size, void* d_ws, size_t ws_size,
                              hipStream_t stream) {
    const float* phi_im = (const float*)d_in[0];
    const float* phi_cli = (const float*)d_in[1];
    const int* t = (const int*)d_in[2];
    const int* traumatic = (const int*)d_in[3];
    float* out = (float*)d_out;

    char* ws = (char*)d_ws;
    unsigned long long* packed = (unsigned long long*)(ws + OFF_PACKED);
    int* cnt = (int*)(ws + OFF_CNT);
    int* catArr = (int*)(ws + OFF_CAT);
    int* lists = (int*)(ws + OFF_LISTS);
    int* posIn = (int*)(ws + OFF_POS);
    unsigned int* colinfo = (unsigned int*)(ws + OFF_COLINFO);
    float* inv_im = (float*)(ws + OFF_INVIM);
    float* inv_cli = (float*)(ws + OFF_INVCLI);
    char* pim = ws + OFF_PIM;
    char* pcli = ws + OFF_PCLI;
    unsigned short* Sc = (unsigned short*)(ws + OFF_SC);

    prepscan_kernel<<<513, 256, 0, stream>>>(
        phi_im, phi_cli, t, traumatic, inv_im, inv_cli, pim, pcli,
        cnt, catArr, lists, posIn, colinfo, packed);
    gemm_kernel<<<GRID_GEMM + 6 * 1024, 256, 0, stream>>>(
        pim, pcli, inv_im, inv_cli, cnt, lists, catArr, Sc, out, packed);
    writer_kernel<<<6 * NROW + 1, 256, 0, stream>>>(Sc, cnt, lists,
                                                    colinfo, out, packed);
}